// Round 2
// baseline (2080.727 us; speedup 1.0000x reference)
//
#include <hip/hip_runtime.h>
#include <hip/hip_bf16.h>

typedef __hip_bfloat16 bf16;
using short8 = __attribute__((ext_vector_type(8))) short;
using f32x4  = __attribute__((ext_vector_type(4))) float;

#define MFMA16(a,b,c) __builtin_amdgcn_mfma_f32_16x16x32_bf16((a),(b),(c),0,0,0)

__device__ __forceinline__ float b2f(bf16 v){ return __bfloat162float(v); }
__device__ __forceinline__ bf16  f2b(float v){ return __float2bfloat16(v); }
__device__ __forceinline__ float sigmf(float x){ return 1.f/(1.f+__expf(-x)); }
__device__ __forceinline__ float tanhfast(float x){
  x = fminf(fmaxf(x,-15.f),15.f);
  float e = __expf(2.f*x);
  return (e-1.f)/(e+1.f);
}
__device__ __forceinline__ short8 ld_frag(const bf16* p){
  return *reinterpret_cast<const short8*>(p);
}

// ---------------- dtype sniff + canonicalize ----------------
// If float inputs are fp32 (as the reference declares), their fp32 exponent
// fields sit in [100,150] for N(0,1)-scale data. If they are bf16-packed,
// the fp32 reinterpretation has exponent ~248..255 (or ~0). Sniff x.

__global__ void k_sniff(const unsigned int* __restrict__ x, int* __restrict__ flag){
  int t = threadIdx.x;
  int good = 0;
  for (int i=t; i<4096; i+=256){
    unsigned w = x[i];
    unsigned e = (w>>23)&0xFFu;
    unsigned m = w & 0x7FFFFFFFu;
    if ((e>=100u && e<=150u) || m==0u) good++;
  }
  __shared__ int sm[256];
  sm[t]=good; __syncthreads();
  if (t==0){ int s=0; for (int k=0;k<256;k++) s+=sm[k]; *flag = (s>2048)?1:0; }
}

struct PtrPack { const void* p[17]; };

// canonical bf16 region layout (element offsets)
#define CAN_X     0
#define CAN_L0W   1500032
#define CAN_L0B   1500992
#define CAN_EE    1501056
#define CAN_CB    1521536
#define CAN_WIH   1521600
#define CAN_WHH   1533888
#define CAN_BIH   1546176
#define CAN_BHH   1546368
#define CAN_IW1   1546560
#define CAN_IB1   1554752
#define CAN_IW2   1554816
#define CAN_IB2   1555584
#define CAN_JW1   1555648
#define CAN_JB1   1559744
#define CAN_JW2   1559808
#define CAN_JB2   1560576
#define CAN_TOT   1560640

__global__ void k_canon(PtrPack pk, const int* __restrict__ flag, bf16* __restrict__ dst){
  static const int offs[17] = {CAN_X,CAN_L0W,CAN_L0B,CAN_EE,CAN_CB,CAN_WIH,CAN_WHH,
    CAN_BIH,CAN_BHH,CAN_IW1,CAN_IB1,CAN_IW2,CAN_IB2,CAN_JW1,CAN_JB1,CAN_JW2,CAN_JB2};
  static const int szs[17]  = {1500000,960,64,20480,64,12288,12288,192,192,8192,64,768,12,4096,64,768,12};
  int t = blockIdx.x*256+threadIdx.x;
  if (t >= CAN_TOT) return;
  int s = 0;
  #pragma unroll
  for (int k=1;k<17;k++) if (t >= offs[k]) s = k;
  int i = t - offs[s];
  float v = 0.f;
  if (i < szs[s]){
    if (*flag) v = ((const float*)pk.p[s])[i];
    else       v = b2f(((const bf16*)pk.p[s])[i]);
  }
  dst[t] = f2b(v);
}

// ---------------- setup kernels ----------------

__global__ void k_hist_deg(const int* __restrict__ dst, int E_, int* __restrict__ cnt){
  int i = blockIdx.x*256+threadIdx.x;
  if (i<E_) atomicAdd(&cnt[dst[i]],1);
}

__global__ void k_hist_graph(const int* __restrict__ batch, int N_, int* __restrict__ gcnt){
  int i = blockIdx.x*256+threadIdx.x;
  if (i<N_) atomicAdd(&gcnt[batch[i]],1);
}

// single-block exclusive scan (wave shuffle-scan + cross-wave)
__global__ __launch_bounds__(1024) void k_scan(const int* __restrict__ cnt, int n,
      int* __restrict__ ptr, int* __restrict__ cursor, float* __restrict__ deg_inv){
  __shared__ int ws[17];
  int tid = threadIdx.x, lane = tid&63, w = tid>>6;
  int run = 0;
  for (int base=0; base<n; base+=1024){
    int i = base + tid;
    int v = (i<n)? cnt[i] : 0;
    int incl = v;
    #pragma unroll
    for (int off=1; off<64; off<<=1){
      int t = __shfl_up(incl, off, 64);
      if (lane>=off) incl += t;
    }
    if (lane==63) ws[w] = incl;
    __syncthreads();
    if (tid==0){ int r=0; for (int k=0;k<16;k++){ int t=ws[k]; ws[k]=r; r+=t; } ws[16]=r; }
    __syncthreads();
    int excl = run + ws[w] + incl - v;
    if (i<n){
      ptr[i] = excl;
      if (cursor)  cursor[i]  = excl;
      if (deg_inv) deg_inv[i] = 1.0f/fmaxf((float)v,1.0f);
    }
    run += ws[16];
    __syncthreads();
  }
  if (tid==0) ptr[n] = run;
}

__global__ void k_scatter(const int* __restrict__ src, const int* __restrict__ dstn,
                          const int* __restrict__ ea, int E_,
                          int* __restrict__ cursor, int* __restrict__ sorted){
  int i = blockIdx.x*256+threadIdx.x;
  if (i<E_){
    int p = atomicAdd(&cursor[dstn[i]],1);
    sorted[p] = src[i]*5 + ea[i];          // packed row index into T
  }
}

__global__ __launch_bounds__(256) void k_lin0(const bf16* __restrict__ x,
      const bf16* __restrict__ w, const bf16* __restrict__ b,
      bf16* __restrict__ out0, bf16* __restrict__ h, int N_){
  int idx = blockIdx.x*256+threadIdx.x;
  int n = idx>>6, o = idx&63;
  if (n>=N_) return;
  float acc = b2f(b[o]);
  #pragma unroll
  for (int k=0;k<15;k++) acc += b2f(x[n*15+k]) * b2f(w[k*64+o]);
  bf16 v = f2b(fmaxf(acc,0.f));
  out0[idx]=v; h[idx]=v;
}

// swizzle edge_embed [5][64][64] -> B-frag layout for 320 output cols, K=64 (KS=2, CB=20)
__global__ void k_swz_wall(const bf16* __restrict__ ee, unsigned short* __restrict__ dst){
  int t = blockIdx.x*256+threadIdx.x;
  if (t>=2560) return;
  int lane=t&63, frag=t>>6, cb=frag>>1, ks=frag&1;
  int c = cb*16 + (lane&15);
  int tt = c>>6, o = c&63;
  #pragma unroll
  for (int j=0;j<8;j++){
    int k = ks*32 + ((lane>>4)<<3) + j;
    dst[t*8+j] = ((const unsigned short*)ee)[tt*4096 + k*64 + o];
  }
}

// generic row-major [K][NC] -> B-frag layout (zero-padded cols)
__global__ void k_swz_gen(const unsigned short* __restrict__ src, int KS, int NC,
                          unsigned short* __restrict__ dst, int nfrag){
  int t = blockIdx.x*256+threadIdx.x;
  if (t >= nfrag*64) return;
  int lane=t&63, frag=t>>6, cb=frag/KS, ks=frag%KS;
  int c = cb*16 + (lane&15);
  #pragma unroll
  for (int j=0;j<8;j++){
    int k = ks*32 + ((lane>>4)<<3) + j;
    dst[t*8+j] = (c<NC)? src[k*NC+c] : (unsigned short)0;
  }
}

// ---------------- per-step kernels ----------------

// T[n][c] = sum_k h[n][k] * Wall[k][c], c in [0,320)
__global__ __launch_bounds__(256) void k_transform(const bf16* __restrict__ h,
      const unsigned short* __restrict__ Wswz, bf16* __restrict__ T, int N_){
  __shared__ unsigned short lds[20480];
  { const int* s=(const int*)Wswz; int* d=(int*)lds;
    for (int i=threadIdx.x;i<10240;i+=256) d[i]=s[i]; }
  __syncthreads();
  int tid=threadIdx.x, lane=tid&63, w=tid>>6, q=lane>>4;
  int nb = blockIdx.x*64 + w*16;
  int ar = nb + (lane&15); if (ar>N_-1) ar=N_-1;
  short8 a0 = ld_frag(h + ar*64 + q*8);
  short8 a1 = ld_frag(h + ar*64 + 32 + q*8);
  const short8* B = reinterpret_cast<const short8*>(lds);
  int colbase = lane&15;
  for (int cb=0; cb<20; cb++){
    f32x4 acc = {0.f,0.f,0.f,0.f};
    acc = MFMA16(a0, B[(cb*2+0)*64+lane], acc);
    acc = MFMA16(a1, B[(cb*2+1)*64+lane], acc);
    int col = cb*16 + colbase;
    #pragma unroll
    for (int r=0;r<4;r++){
      int row = nb + q*4 + r;
      if (row < N_) T[row*320 + col] = f2b(acc[r]);
    }
  }
}

// one wave per node: agg = sum_{e in CSR[n]} T[packed_e][lane]; m = relu(agg*deginv + bias)
__global__ __launch_bounds__(256) void k_aggregate(const bf16* __restrict__ T,
      const int* __restrict__ sorted, const int* __restrict__ row_ptr,
      const float* __restrict__ deg_inv, const bf16* __restrict__ conv_bias,
      bf16* __restrict__ m, int N_){
  int w = threadIdx.x>>6, lane = threadIdx.x&63;
  int n = blockIdx.x*4 + w;
  if (n>=N_) return;
  int s = row_ptr[n], e = row_ptr[n+1];
  float acc = 0.f;
  for (int base=s; base<e; base+=64){
    int idx = base + lane;
    int pk = (idx<e)? sorted[idx] : 0;
    int cnt = min(64, e-base);
    #pragma unroll 4
    for (int j=0;j<cnt;j++){
      int row = __shfl(pk, j, 64);
      acc += b2f(T[row*64 + lane]);
    }
  }
  float mv = acc*deg_inv[n] + b2f(conv_bias[lane]);
  m[n*64+lane] = f2b(fmaxf(mv,0.f));
}

// GRU: gx = m@Wih+bih, gh = h@Whh+bhh (torch gate order r,z,n); h in-place
__global__ __launch_bounds__(256) void k_gru(const bf16* __restrict__ m, bf16* __restrict__ h,
      const unsigned short* __restrict__ W /* Wih(12288) then Whh(12288) shorts */,
      const bf16* __restrict__ bih, const bf16* __restrict__ bhh, int N_){
  __shared__ unsigned short lds[24576];
  { const int* s=(const int*)W; int* d=(int*)lds;
    for (int i=threadIdx.x;i<12288;i+=256) d[i]=s[i]; }
  __syncthreads();
  int tid=threadIdx.x, lane=tid&63, w=tid>>6, q=lane>>4;
  int nb = blockIdx.x*64 + w*16;
  int ar = nb + (lane&15); if (ar>N_-1) ar=N_-1;
  short8 am0 = ld_frag(m + ar*64 + q*8);
  short8 am1 = ld_frag(m + ar*64 + 32 + q*8);
  short8 ah0 = ld_frag(h + ar*64 + q*8);
  short8 ah1 = ld_frag(h + ar*64 + 32 + q*8);
  const short8* B = reinterpret_cast<const short8*>(lds);
  f32x4 ax[12], ag[12];
  for (int cb=0; cb<12; cb++){
    f32x4 a = {0.f,0.f,0.f,0.f};
    a = MFMA16(am0, B[(cb*2+0)*64+lane], a);
    a = MFMA16(am1, B[(cb*2+1)*64+lane], a);
    ax[cb]=a;
    f32x4 b = {0.f,0.f,0.f,0.f};
    b = MFMA16(ah0, B[(24+cb*2+0)*64+lane], b);
    b = MFMA16(ah1, B[(24+cb*2+1)*64+lane], b);
    ag[cb]=b;
  }
  int colb = lane&15;
  #pragma unroll
  for (int cb=0; cb<4; cb++){
    int o = cb*16 + colb;
    float bxr=b2f(bih[o]), bxz=b2f(bih[o+64]), bxn=b2f(bih[o+128]);
    float bhr=b2f(bhh[o]), bhz=b2f(bhh[o+64]), bhn=b2f(bhh[o+128]);
    #pragma unroll
    for (int r=0;r<4;r++){
      int row = nb + q*4 + r;
      if (row < N_){
        float xr = ax[cb][r]+bxr, xz = ax[cb+4][r]+bxz, xn = ax[cb+8][r]+bxn;
        float hr = ag[cb][r]+bhr, hz = ag[cb+4][r]+bhz, hn = ag[cb+8][r]+bhn;
        float rg = sigmf(xr+hr);
        float zg = sigmf(xz+hz);
        float ng = tanhfast(xn + rg*hn);
        float ho = b2f(h[row*64+o]);
        h[row*64+o] = f2b((1.f-zg)*ng + zg*ho);
      }
    }
  }
}

// ---------------- readout ----------------

__global__ __launch_bounds__(256) void k_read1(const bf16* __restrict__ h, const bf16* __restrict__ out0,
      const unsigned short* __restrict__ W /* iw1swz(8192) then jw1swz(4096) shorts */,
      const bf16* __restrict__ ib1, const bf16* __restrict__ jb1,
      bf16* __restrict__ s1, bf16* __restrict__ t1, int N_){
  __shared__ unsigned short lds[12288];
  { const int* s=(const int*)W; int* d=(int*)lds;
    for (int i=threadIdx.x;i<6144;i+=256) d[i]=s[i]; }
  __syncthreads();
  int tid=threadIdx.x, lane=tid&63, w=tid>>6, q=lane>>4;
  int nb = blockIdx.x*64 + w*16;
  int ar = nb + (lane&15); if (ar>N_-1) ar=N_-1;
  short8 ah0 = ld_frag(h + ar*64 + q*8),    ah1 = ld_frag(h + ar*64 + 32 + q*8);
  short8 ao0 = ld_frag(out0 + ar*64 + q*8), ao1 = ld_frag(out0 + ar*64 + 32 + q*8);
  const short8* Bi = reinterpret_cast<const short8*>(lds);
  const short8* Bj = reinterpret_cast<const short8*>(lds + 8192);
  int colb = lane&15;
  for (int cb=0; cb<4; cb++){
    f32x4 ai = {0.f,0.f,0.f,0.f};
    ai = MFMA16(ah0, Bi[(cb*4+0)*64+lane], ai);
    ai = MFMA16(ah1, Bi[(cb*4+1)*64+lane], ai);
    ai = MFMA16(ao0, Bi[(cb*4+2)*64+lane], ai);
    ai = MFMA16(ao1, Bi[(cb*4+3)*64+lane], ai);
    f32x4 aj = {0.f,0.f,0.f,0.f};
    aj = MFMA16(ah0, Bj[(cb*2+0)*64+lane], aj);
    aj = MFMA16(ah1, Bj[(cb*2+1)*64+lane], aj);
    int col = cb*16 + colb;
    float bi=b2f(ib1[col]), bj=b2f(jb1[col]);
    #pragma unroll
    for (int r=0;r<4;r++){
      int row = nb + q*4 + r;
      if (row < N_){
        s1[row*64+col] = f2b(sigmf(ai[r]+bi));
        t1[row*64+col] = f2b(sigmf(aj[r]+bj));
      }
    }
  }
}

__global__ __launch_bounds__(256) void k_read2(const bf16* __restrict__ s1, const bf16* __restrict__ t1,
      const unsigned short* __restrict__ iw2swz, const unsigned short* __restrict__ jw2swz,
      const bf16* __restrict__ ib2, const bf16* __restrict__ jb2,
      float* __restrict__ gated, int N_){
  int tid=threadIdx.x, lane=tid&63, w=tid>>6, q=lane>>4;
  int nb = blockIdx.x*64 + w*16;
  int ar = nb + (lane&15); if (ar>N_-1) ar=N_-1;
  short8 as0 = ld_frag(s1 + ar*64 + q*8), as1 = ld_frag(s1 + ar*64 + 32 + q*8);
  short8 at0 = ld_frag(t1 + ar*64 + q*8), at1 = ld_frag(t1 + ar*64 + 32 + q*8);
  const short8* Bi = reinterpret_cast<const short8*>(iw2swz);
  const short8* Bj = reinterpret_cast<const short8*>(jw2swz);
  f32x4 ai = {0.f,0.f,0.f,0.f};
  ai = MFMA16(as0, Bi[lane], ai);
  ai = MFMA16(as1, Bi[64+lane], ai);
  f32x4 aj = {0.f,0.f,0.f,0.f};
  aj = MFMA16(at0, Bj[lane], aj);
  aj = MFMA16(at1, Bj[64+lane], aj);
  int col = lane&15;
  if (col<12){
    float bi=b2f(ib2[col]), bj=b2f(jb2[col]);
    #pragma unroll
    for (int r=0;r<4;r++){
      int row = nb + q*4 + r;
      if (row < N_) gated[row*12+col] = sigmf(ai[r]+bi)*(aj[r]+bj);
    }
  }
}

__global__ __launch_bounds__(256) void k_graphsum(const float* __restrict__ gated,
      const int* __restrict__ gptr, const int* __restrict__ flag, void* __restrict__ outp){
  int g = blockIdx.x;
  int s = gptr[g], e = gptr[g+1];
  int tid = threadIdx.x;
  int c = tid & 15, rg = tid >> 4;        // 16 row-groups x 16 cols
  float acc = 0.f;
  if (c < 12)
    for (int row = s + rg; row < e; row += 16) acc += gated[row*12 + c];
  __shared__ float sm[256];
  sm[tid] = acc;
  __syncthreads();
  if (rg == 0 && c < 12){
    float t = 0.f;
    for (int k=0;k<16;k++) t += sm[k*16 + c];
    if (*flag) ((float*)outp)[g*12 + c] = t;
    else       ((bf16*) outp)[g*12 + c] = f2b(t);
  }
}

// ---------------- launch ----------------

extern "C" void kernel_launch(void* const* d_in, const int* in_sizes, int n_in,
                              void* d_out, int out_size, void* d_ws, size_t ws_size,
                              hipStream_t stream){
  const int*  ei    = (const int*) d_in[1];
  const int*  ea    = (const int*) d_in[2];
  const int*  batch = (const int*) d_in[3];

  const int N_ = in_sizes[3];        // 100000
  const int E_ = in_sizes[2];        // 3200000
  const int G_ = out_size / 12;      // 256

  char* ws = (char*)d_ws;
  size_t off = 0;
  auto alloc = [&](size_t bytes)->size_t{
    size_t o = off; off += (bytes + 255) & ~(size_t)255; return o;
  };

  size_t oT      = alloc((size_t)N_*320*2);     // 64 MB; later aliased for s1/t1/gated
  size_t oOut0   = alloc((size_t)N_*64*2);
  size_t oH      = alloc((size_t)N_*64*2);
  size_t oM      = alloc((size_t)N_*64*2);
  size_t oSorted = alloc((size_t)E_*4);
  size_t oCanon  = alloc((size_t)CAN_TOT*2);
  size_t oCnt    = alloc((size_t)(N_+G_)*4);    // cnt[N] then gcnt[G], zeroed together
  size_t oRowPtr = alloc((size_t)(N_+1)*4);
  size_t oCursor = alloc((size_t)N_*4);
  size_t oDegInv = alloc((size_t)N_*4);
  size_t oGptr   = alloc((size_t)(G_+1)*4);
  size_t oFlag   = alloc(256);
  size_t oWall   = alloc((size_t)20480*2);
  size_t oWgru   = alloc((size_t)24576*2);      // Wih swz + Whh swz
  size_t oWr1    = alloc((size_t)12288*2);      // iw1 swz + jw1 swz
  size_t oWiw2   = alloc((size_t)1024*2);
  size_t oWjw2   = alloc((size_t)1024*2);

  bf16*  T       = (bf16*)(ws + oT);
  bf16*  s1      = (bf16*)(ws + oT);                    // alias (T dead at readout)
  bf16*  t1      = (bf16*)(ws + oT + 16000000);
  float* gated   = (float*)(ws + oT + 32000000);
  bf16*  out0    = (bf16*)(ws + oOut0);
  bf16*  h       = (bf16*)(ws + oH);
  bf16*  m       = (bf16*)(ws + oM);
  int*   sorted  = (int*)(ws + oSorted);
  bf16*  can     = (bf16*)(ws + oCanon);
  int*   cnt     = (int*)(ws + oCnt);
  int*   gcnt    = cnt + N_;
  int*   row_ptr = (int*)(ws + oRowPtr);
  int*   cursor  = (int*)(ws + oCursor);
  float* deg_inv = (float*)(ws + oDegInv);
  int*   gptr    = (int*)(ws + oGptr);
  int*   flag    = (int*)(ws + oFlag);
  unsigned short* wall  = (unsigned short*)(ws + oWall);
  unsigned short* wgru  = (unsigned short*)(ws + oWgru);
  unsigned short* wr1   = (unsigned short*)(ws + oWr1);
  unsigned short* wiw2s = (unsigned short*)(ws + oWiw2);
  unsigned short* wjw2s = (unsigned short*)(ws + oWjw2);

  // canonical views
  const bf16* xC    = can + CAN_X;
  const bf16* l0wC  = can + CAN_L0W;
  const bf16* l0bC  = can + CAN_L0B;
  const bf16* eeC   = can + CAN_EE;
  const bf16* cbC   = can + CAN_CB;
  const bf16* wihC  = can + CAN_WIH;
  const bf16* whhC  = can + CAN_WHH;
  const bf16* bihC  = can + CAN_BIH;
  const bf16* bhhC  = can + CAN_BHH;
  const bf16* iw1C  = can + CAN_IW1;
  const bf16* ib1C  = can + CAN_IB1;
  const bf16* iw2C  = can + CAN_IW2;
  const bf16* ib2C  = can + CAN_IB2;
  const bf16* jw1C  = can + CAN_JW1;
  const bf16* jb1C  = can + CAN_JB1;
  const bf16* jw2C  = can + CAN_JW2;
  const bf16* jb2C  = can + CAN_JB2;

  PtrPack pk;
  pk.p[0]=d_in[0];  pk.p[1]=d_in[4];  pk.p[2]=d_in[5];  pk.p[3]=d_in[6];
  pk.p[4]=d_in[7];  pk.p[5]=d_in[8];  pk.p[6]=d_in[9];  pk.p[7]=d_in[10];
  pk.p[8]=d_in[11]; pk.p[9]=d_in[12]; pk.p[10]=d_in[13]; pk.p[11]=d_in[14];
  pk.p[12]=d_in[15]; pk.p[13]=d_in[16]; pk.p[14]=d_in[17]; pk.p[15]=d_in[18];
  pk.p[16]=d_in[19];

  const int gE  = (E_+255)/256;
  const int gN  = (N_+255)/256;
  const int gNw = (N_+63)/64;      // 64 nodes / block (4 waves x 16)
  const int gAg = (N_+3)/4;        // 4 nodes / block (wave each)

  // --- setup ---
  k_sniff<<<1, 256, 0, stream>>>((const unsigned int*)d_in[0], flag);
  k_canon<<<(CAN_TOT+255)/256, 256, 0, stream>>>(pk, flag, can);
  hipMemsetAsync(ws + oCnt, 0, (size_t)(N_+G_)*4, stream);
  k_hist_deg  <<<gE, 256, 0, stream>>>(ei + E_, E_, cnt);
  k_hist_graph<<<gN, 256, 0, stream>>>(batch, N_, gcnt);
  k_scan<<<1, 1024, 0, stream>>>(cnt, N_, row_ptr, cursor, deg_inv);
  k_scan<<<1, 1024, 0, stream>>>(gcnt, G_, gptr, nullptr, nullptr);
  k_scatter<<<gE, 256, 0, stream>>>(ei, ei + E_, ea, E_, cursor, sorted);
  k_lin0<<<(N_*64+255)/256, 256, 0, stream>>>(xC, l0wC, l0bC, out0, h, N_);
  k_swz_wall<<<10, 256, 0, stream>>>(eeC, wall);
  k_swz_gen<<<6, 256, 0, stream>>>((const unsigned short*)wihC, 2, 192, wgru,          24);
  k_swz_gen<<<6, 256, 0, stream>>>((const unsigned short*)whhC, 2, 192, wgru + 12288,  24);
  k_swz_gen<<<4, 256, 0, stream>>>((const unsigned short*)iw1C, 4,  64, wr1,           16);
  k_swz_gen<<<2, 256, 0, stream>>>((const unsigned short*)jw1C, 2,  64, wr1 + 8192,     8);
  k_swz_gen<<<1, 256, 0, stream>>>((const unsigned short*)iw2C, 2,  12, wiw2s,          2);
  k_swz_gen<<<1, 256, 0, stream>>>((const unsigned short*)jw2C, 2,  12, wjw2s,          2);

  // --- 6 propagation steps ---
  for (int step = 0; step < 6; ++step){
    k_transform<<<gNw, 256, 0, stream>>>(h, wall, T, N_);
    k_aggregate<<<gAg, 256, 0, stream>>>(T, sorted, row_ptr, deg_inv, cbC, m, N_);
    k_gru<<<gNw, 256, 0, stream>>>(m, h, wgru, bihC, bhhC, N_);
  }

  // --- readout ---
  k_read1<<<gNw, 256, 0, stream>>>(h, out0, wr1, ib1C, jb1C, s1, t1, N_);
  k_read2<<<gNw, 256, 0, stream>>>(s1, t1, wiw2s, wjw2s, ib2C, jb2C, gated, N_);
  k_graphsum<<<G_, 256, 0, stream>>>(gated, gptr, flag, d_out);
}